// Round 1
// baseline (736.296 us; speedup 1.0000x reference)
//
#include <hip/hip_runtime.h>

// Problem constants (match the JAX reference).
constexpr int Zd = 224;
constexpr int Yd = 512;
constexpr int Xd = 512;
constexpr int Pd = 15;          // spectral predictors
constexpr int WDIM = Pd + 4;    // 19 weights per band
constexpr float MAXV = 32767.0f;   // 2^15 - 1
constexpr float MINV = -32768.0f;  // -2^15

// Outputs (preds, resids) depend only on image and the INPUT weights:
// the scan's weight update for band z happens after band z's pred and is
// never read by any other band. So the whole thing is parallel over z.
//
// pred[z,y,x] = clip( cn*north + cw*west + cnw*nw + sum_k w[4+k]*image[z-15+k,y,x] )
// with cn = w0 + w3/3 etc. (folding the "fourth" predictor).
__global__ __launch_bounds__(256) void spec_pred_kernel(
    const float* __restrict__ image,
    const float* __restrict__ weights,
    float* __restrict__ preds,
    float* __restrict__ resids)
{
    const int z = blockIdx.z;
    const int y = blockIdx.y * blockDim.y + threadIdx.y;
    const int x = threadIdx.x * 4;  // blockDim.x = 128 covers X=512 as float4

    const long long YX = (long long)Yd * Xd;
    const long long rowoff = (long long)z * YX + (long long)y * Xd;
    const float* row = image + rowoff;

    // Per-band weights: uniform across the block (z is uniform) -> scalar loads.
    const float* wr = weights + z * WDIM;
    const float w3 = wr[3] * (1.0f / 3.0f);
    const float cn  = wr[0] + w3;
    const float cw  = wr[1] + w3;
    const float cnw = wr[2] + w3;

    // Current band: self (for resid + west), north row (for north + nw).
    const float4 self = *(const float4*)(row + x);
    float4 north = make_float4(0.f, 0.f, 0.f, 0.f);
    float sleft = 0.f, nleft = 0.f;
    if (y > 0) {
        const float* nrow = row - Xd;
        north = *(const float4*)(nrow + x);
        if (x > 0) nleft = nrow[x - 1];
    }
    if (x > 0) sleft = row[x - 1];

    // west = self shifted right by one; nw = north shifted right by one.
    const float4 west = make_float4(sleft, self.x, self.y, self.z);
    const float4 nwv  = make_float4(nleft, north.x, north.y, north.z);

    float p0 = cn * north.x + cw * west.x + cnw * nwv.x;
    float p1 = cn * north.y + cw * west.y + cnw * nwv.y;
    float p2 = cn * north.z + cw * west.z + cnw * nwv.z;
    float p3 = cn * north.w + cw * west.w + cnw * nwv.w;

    // Spectral predictors: previous 15 bands at the same (y,x).
    // zk >= 0 test is uniform across the block (z uniform) -> no divergence.
#pragma unroll
    for (int k = 0; k < Pd; ++k) {
        const int zk = z - Pd + k;
        if (zk >= 0) {
            const float4 s = *(const float4*)(image + (long long)zk * YX +
                                              (long long)y * Xd + x);
            const float wk = wr[4 + k];
            p0 = fmaf(wk, s.x, p0);
            p1 = fmaf(wk, s.y, p1);
            p2 = fmaf(wk, s.z, p2);
            p3 = fmaf(wk, s.w, p3);
        }
    }

    p0 = fminf(fmaxf(p0, MINV), MAXV);
    p1 = fminf(fmaxf(p1, MINV), MAXV);
    p2 = fminf(fmaxf(p2, MINV), MAXV);
    p3 = fminf(fmaxf(p3, MINV), MAXV);

    const float4 pv = make_float4(p0, p1, p2, p3);
    const float4 rv = make_float4(self.x - p0, self.y - p1,
                                  self.z - p2, self.w - p3);
    *(float4*)(preds  + rowoff + x) = pv;
    *(float4*)(resids + rowoff + x) = rv;
}

extern "C" void kernel_launch(void* const* d_in, const int* in_sizes, int n_in,
                              void* d_out, int out_size, void* d_ws, size_t ws_size,
                              hipStream_t stream) {
    const float* image   = (const float*)d_in[0];
    const float* weights = (const float*)d_in[1];
    // d_in[2] (local_sums) only feeds the discarded carry — unused.

    float* preds  = (float*)d_out;
    float* resids = (float*)d_out + (long long)Zd * Yd * Xd;

    dim3 block(128, 2, 1);               // 256 threads, full X row per y
    dim3 grid(1, Yd / 2, Zd);            // 256 * 224 blocks
    spec_pred_kernel<<<grid, block, 0, stream>>>(image, weights, preds, resids);
}

// Round 2
// 626.387 us; speedup vs baseline: 1.1755x; 1.1755x over previous
//
#include <hip/hip_runtime.h>

// Problem constants (match the JAX reference).
constexpr int Zd = 224;
constexpr int Yd = 512;
constexpr int Xd = 512;
constexpr int Pd = 15;          // spectral predictors
constexpr int WDIM = Pd + 4;    // 19 weights per band
constexpr float MAXV = 32767.0f;   // 2^15 - 1
constexpr float MINV = -32768.0f;  // -2^15

constexpr int NCHUNK = 4;            // z-chunks (parallelism: 4 blocks/CU)
constexpr int CHUNK  = Zd / NCHUNK;  // 56 bands per chunk

// Outputs (preds, resids) depend only on image and the INPUT weights (the
// scan's weight update for band z is never read by any other band's output).
//
// pred[z,y,x] = clip( cn*north + cw*west + cnw*nw
//                     + sum_{k=0..14} w[4+k]*image[z-15+k,y,x] )
// with cn = w0 + w3/3 etc. (folding the "fourth" predictor).
//
// Rolling-window kernel: thread owns (y, x..x+3), marches z through its
// chunk keeping the previous 15 bands' self-values in registers. This cuts
// cache read traffic ~4.5x vs the z-parallel version (which was L3-BW bound).
__global__ __launch_bounds__(256, 4) void spec_pred_roll(
    const float* __restrict__ image,
    const float* __restrict__ weights,
    float* __restrict__ preds,
    float* __restrict__ resids)
{
    const int y  = blockIdx.y * 2 + threadIdx.y;   // blockDim = (128, 2)
    const int x  = threadIdx.x * 4;                // 128 threads cover X=512
    const int z0 = blockIdx.x * CHUNK;

    const long long YX  = (long long)Yd * Xd;
    const long long yx  = (long long)y * Xd + x;

    // Rolling history: h[k] holds image[z-15+k, y, x..x+3].
    float4 h[Pd];
#pragma unroll
    for (int k = 0; k < Pd; ++k) {
        const int zk = z0 - Pd + k;               // uniform branch (z0 uniform)
        h[k] = (zk >= 0) ? *(const float4*)(image + (long long)zk * YX + yx)
                         : make_float4(0.f, 0.f, 0.f, 0.f);
    }

    const float* row0 = image + yx;               // &image[0, y, x]

    for (int i = 0; i < CHUNK; ++i) {
        const int z = z0 + i;                     // < 224 always (4*56 = 224)
        const float* row = row0 + (long long)z * YX;

        // Per-band weights: address is wave-uniform -> scalar loads.
        const float* wr = weights + z * WDIM;
        const float w3  = wr[3] * (1.0f / 3.0f);
        const float cn  = wr[0] + w3;
        const float cw  = wr[1] + w3;
        const float cnw = wr[2] + w3;

        // Current band: self (resid + west source), north row (north + nw).
        const float4 self = *(const float4*)(row);
        float4 north = make_float4(0.f, 0.f, 0.f, 0.f);
        float sleft = 0.f, nleft = 0.f;
        if (y > 0) {
            const float* nrow = row - Xd;
            north = *(const float4*)(nrow);
            if (x > 0) nleft = nrow[-1];
        }
        if (x > 0) sleft = row[-1];

        const float4 west = make_float4(sleft, self.x, self.y, self.z);
        const float4 nwv  = make_float4(nleft, north.x, north.y, north.z);

        float p0 = cn * north.x + cw * west.x + cnw * nwv.x;
        float p1 = cn * north.y + cw * west.y + cnw * nwv.y;
        float p2 = cn * north.z + cw * west.z + cnw * nwv.z;
        float p3 = cn * north.w + cw * west.w + cnw * nwv.w;

        // Spectral predictors from the register window (bands z-15 .. z-1).
#pragma unroll
        for (int k = 0; k < Pd; ++k) {
            const float wk = wr[4 + k];
            p0 = fmaf(wk, h[k].x, p0);
            p1 = fmaf(wk, h[k].y, p1);
            p2 = fmaf(wk, h[k].z, p2);
            p3 = fmaf(wk, h[k].w, p3);
        }

        p0 = fminf(fmaxf(p0, MINV), MAXV);
        p1 = fminf(fmaxf(p1, MINV), MAXV);
        p2 = fminf(fmaxf(p2, MINV), MAXV);
        p3 = fminf(fmaxf(p3, MINV), MAXV);

        const long long o = (long long)z * YX + yx;
        *(float4*)(preds  + o) = make_float4(p0, p1, p2, p3);
        *(float4*)(resids + o) = make_float4(self.x - p0, self.y - p1,
                                             self.z - p2, self.w - p3);

        // Advance the window (constant indices -> stays in registers).
#pragma unroll
        for (int k = 0; k < Pd - 1; ++k) h[k] = h[k + 1];
        h[Pd - 1] = self;
    }
}

extern "C" void kernel_launch(void* const* d_in, const int* in_sizes, int n_in,
                              void* d_out, int out_size, void* d_ws, size_t ws_size,
                              hipStream_t stream) {
    const float* image   = (const float*)d_in[0];
    const float* weights = (const float*)d_in[1];
    // d_in[2] (local_sums) only feeds the discarded carry — unused.

    float* preds  = (float*)d_out;
    float* resids = (float*)d_out + (long long)Zd * Yd * Xd;

    dim3 block(128, 2, 1);                // 256 threads, full X row per y
    dim3 grid(NCHUNK, Yd / 2, 1);         // 4 z-chunks x 256 y-blocks = 1024
    spec_pred_roll<<<grid, block, 0, stream>>>(image, weights, preds, resids);
}